// Round 4
// baseline (162.305 us; speedup 1.0000x reference)
//
#include <hip/hip_runtime.h>
#include <hip/hip_bf16.h>
#include <math.h>

typedef __bf16 bf16;
typedef bf16 bf16x8 __attribute__((ext_vector_type(8)));
typedef bf16 bf16x4 __attribute__((ext_vector_type(4)));
typedef float f32x4 __attribute__((ext_vector_type(4)));

#define N_NODES 8192
#define DIN 256
#define DOUT 256
#define KCAT 512
#define EPSF 1e-8f
#define KSPLIT 4
#define KBLK 2048          // K per block
#define BM 64
#define BK 32
#define NT (KBLK / BK)     // 64 tiles
#define BBASE 4096         // A region 64 rows x 64B = 4 KB, then B region
#define BUFSZ 20480        // A 4 KB + B 16 KB

__device__ __forceinline__ f32x4 mfma16(bf16x8 a, bf16x8 b, f32x4 c) {
    return __builtin_amdgcn_mfma_f32_16x16x32_bf16(a, b, c, 0, 0, 0);
}

#define WAITVM(N) asm volatile("s_waitcnt vmcnt(" #N ")" ::: "memory")
#define WAITLGKM  asm volatile("s_waitcnt lgkmcnt(0)" ::: "memory")
#define BAR       __builtin_amdgcn_s_barrier()

// ---------------- K0: W_w [256x256] -> WwT[n][k] bf16 ; W_fc [512x256] -> WfcT[n][k] bf16
__global__ __launch_bounds__(256) void k0_prep(const float* __restrict__ Ww,
                                               const float* __restrict__ Wfc,
                                               bf16* __restrict__ WwT,
                                               bf16* __restrict__ WfcT) {
    int tid = blockIdx.x * 256 + threadIdx.x;
    if (tid < 256 * 256) {
        int n = tid >> 8, k = tid & 255;
        WwT[n * 256 + k] = (bf16)Ww[k * 256 + n];
    }
    if (tid < 256 * 512) {
        int n = tid >> 9, k = tid & 511;
        WfcT[n * 512 + k] = (bf16)Wfc[k * 256 + n];
    }
}

// ---------------- K1: hT[col][m] = bf16(relu(X @ W_w + b_w))
__global__ __launch_bounds__(128) void k1_h(const float* __restrict__ X,
                                            const bf16* __restrict__ WwT,
                                            const float* __restrict__ bw,
                                            bf16* __restrict__ hT) {
    const int lane = threadIdx.x & 63;
    const int wid  = threadIdx.x >> 6;   // 0..1
    const int m0   = blockIdx.x * 16;
    const int lrow = lane & 15;
    const int lk8  = (lane >> 4) * 8;

    f32x4 acc[8];
#pragma unroll
    for (int i = 0; i < 8; ++i) acc[i] = {0.f, 0.f, 0.f, 0.f};

#pragma unroll
    for (int ks = 0; ks < DIN; ks += 32) {
        const float* xp = X + (size_t)(m0 + lrow) * DIN + ks + lk8;
        f32x4 x0 = *reinterpret_cast<const f32x4*>(xp);
        f32x4 x1 = *reinterpret_cast<const f32x4*>(xp + 4);
        bf16x8 a;
#pragma unroll
        for (int j = 0; j < 4; ++j) { a[j] = (bf16)x0[j]; a[4 + j] = (bf16)x1[j]; }
#pragma unroll
        for (int nb = 0; nb < 8; ++nb) {
            int col = wid * 128 + nb * 16 + lrow;
            bf16x8 b = *reinterpret_cast<const bf16x8*>(WwT + (size_t)col * DIN + ks + lk8);
            acc[nb] = mfma16(a, b, acc[nb]);
        }
    }
    const int mrow = m0 + (lane >> 4) * 4;
#pragma unroll
    for (int nb = 0; nb < 8; ++nb) {
        int col = wid * 128 + nb * 16 + lrow;
        float bias = bw[col];
        bf16x4 hv;
#pragma unroll
        for (int j = 0; j < 4; ++j) {
            float v = acc[nb][j] + bias;
            hv[j] = (bf16)(v > 0.f ? v : 0.f);
        }
        *reinterpret_cast<bf16x4*>(hT + (size_t)col * N_NODES + mrow) = hv;
    }
}

// ---------------- K2: partial pooled = A[m0:m0+64, kbase:kbase+2048] @ h[k-range]
// grid 512 = 128 M-blocks x 4 K-splits, 512 thr (8 waves as 2x4 of 32x64 tiles).
// LDS 42 KB -> 2 blocks/CU co-resident (the TLP that hides barrier/DMA stalls).
// A: coalesced f32x4 -> cvt bf16 -> swizzled ds_write_b64 (4 KB/tile).
// B: global_load_lds 16B/lane, source-pre-swizzled, linear LDS dest (16 KB/tile).
// Swizzle (both operands, 64B row pitch): seg_phys = seg ^ ((row>>1)&3).
// 2-phase counted-vmcnt pipeline, raw s_barrier, never vmcnt(0) mid-loop.
// rowsum: waves with wn == (tile&3) do 2 extra MFMA with all-ones B.
__global__ __launch_bounds__(512, 4) void k2_pool(const float* __restrict__ A,
                                                  const bf16* __restrict__ hT,
                                                  float* __restrict__ part,
                                                  float* __restrict__ rsG) {
    __shared__ __align__(16) unsigned char lds[2][BUFSZ];
    __shared__ float rsp[4][BM];
    const int t    = threadIdx.x;
    const int lane = t & 63;
    const int wid  = t >> 6;        // 0..7
    const int wr   = wid >> 2;      // 0..1  (row half: 32 rows)
    const int wn   = wid & 3;       // 0..3  (col quarter: 64 cols)
    const int lrow = lane & 15;
    const int lk4  = lane >> 4;     // 0..3 (16B k-seg)
    const int mblk = blockIdx.x & 127;
    const int ks   = blockIdx.x >> 7;
    const int m0   = mblk * BM;
    const int kbase = ks * KBLK;

    f32x4 acc[2][4];
    f32x4 sums[2];
#pragma unroll
    for (int i = 0; i < 2; ++i) {
        sums[i] = {0.f, 0.f, 0.f, 0.f};
#pragma unroll
        for (int j = 0; j < 4; ++j) acc[i][j] = {0.f, 0.f, 0.f, 0.f};
    }
    bf16x8 bOne;
#pragma unroll
    for (int j = 0; j < 8; ++j) bOne[j] = (bf16)1.0f;

    // ---- A staging: thread t -> row t>>3, f32x4 at float-pos (t&7)*4
    const int arow = t >> 3;
    const int apos = t & 7;
    const float* aSrc = A + (size_t)(m0 + arow) * N_NODES + kbase + apos * 4;
    const int awb = arow * 64 + ((((apos >> 1) ^ ((arow >> 1) & 3))) << 4) + (apos & 1) * 8;

    // ---- B DMA (2 rounds): idx = r*512+t -> col=idx>>2, s_phys=idx&3,
    //      global seg gs = s_phys ^ ((col>>1)&3); LDS dest linear (base wave-uniform)
    const bf16* bsrc[2];
    int bdst[2];
#pragma unroll
    for (int r = 0; r < 2; ++r) {
        int idx = r * 512 + t;
        int col = idx >> 2;
        int gs  = (idx & 3) ^ ((col >> 1) & 3);
        bsrc[r] = hT + (size_t)col * N_NODES + kbase + gs * 8;
        bdst[r] = BBASE + r * 8192 + wid * 1024;   // + lane*16 applied by HW
    }

    // ---- fragment read byte offsets
    int aOff[2], bOff[4];
#pragma unroll
    for (int mf = 0; mf < 2; ++mf) {
        int row = wr * 32 + mf * 16 + lrow;
        aOff[mf] = row * 64 + ((lk4 ^ ((row >> 1) & 3)) << 4);
    }
#pragma unroll
    for (int nf = 0; nf < 4; ++nf) {
        int col = wn * 64 + nf * 16 + lrow;
        bOff[nf] = BBASE + col * 64 + ((lk4 ^ ((col >> 1) & 3)) << 4);
    }

    f32x4 ra;

#define ALOAD(tile) do { ra = *reinterpret_cast<const f32x4*>(aSrc + (size_t)(tile) * BK); } while (0)

#define CVTWRITE(bufidx) do {                                                 \
        bf16x4 w_;                                                            \
        _Pragma("unroll")                                                     \
        for (int j = 0; j < 4; ++j) w_[j] = (bf16)ra[j];                      \
        *reinterpret_cast<bf16x4*>(&lds[bufidx][awb]) = w_;                   \
    } while (0)

#define BDMA(tile, bufidx) do {                                               \
        _Pragma("unroll")                                                     \
        for (int r_ = 0; r_ < 2; ++r_) {                                      \
            __builtin_amdgcn_global_load_lds(                                 \
                (const __attribute__((address_space(1))) void*)(bsrc[r_] + (size_t)(tile) * BK), \
                (__attribute__((address_space(3))) void*)&lds[bufidx][bdst[r_]], \
                16, 0, 0);                                                    \
        }                                                                     \
    } while (0)

#define COMPUTE(bufidx, tile) do {                                            \
        bf16x8 af_[2], bf_[4];                                                \
        _Pragma("unroll")                                                     \
        for (int f = 0; f < 2; ++f)                                           \
            af_[f] = *reinterpret_cast<const bf16x8*>(&lds[bufidx][aOff[f]]); \
        _Pragma("unroll")                                                     \
        for (int f = 0; f < 4; ++f)                                           \
            bf_[f] = *reinterpret_cast<const bf16x8*>(&lds[bufidx][bOff[f]]); \
        _Pragma("unroll")                                                     \
        for (int mf = 0; mf < 2; ++mf)                                        \
            _Pragma("unroll")                                                 \
            for (int nf = 0; nf < 4; ++nf)                                    \
                acc[mf][nf] = mfma16(af_[mf], bf_[nf], acc[mf][nf]);          \
        if (wn == ((tile) & 3)) {                                             \
            sums[0] = mfma16(af_[0], bOne, sums[0]);                          \
            sums[1] = mfma16(af_[1], bOne, sums[1]);                          \
        }                                                                     \
    } while (0)

    // ---------------- prologue
    ALOAD(0); BDMA(0, 0);
    CVTWRITE(0);                 // compiler inserts precise vmcnt for ra use
    ALOAD(1); BDMA(1, 1);
    WAITVM(3);                   // B(0) done; A(1)+B(1) (3 newest) may remain
    WAITLGKM;
    BAR;                         // tile 0 ready

    // ---------------- main loop
    for (int tt = 0; tt < NT - 2; ++tt) {
        CVTWRITE((tt + 1) & 1);  // compiler waits ra=A(tt+1) precisely
        COMPUTE(tt & 1, tt);
        ALOAD(tt + 2);
        WAITVM(1);               // B(tt+1) done; A(tt+2) stays in flight
        WAITLGKM;
        BAR;                     // tile tt+1 ready; all waves done with buf[tt&1]
        BDMA(tt + 2, tt & 1);
    }
    // ---------------- tail
    CVTWRITE((NT - 1) & 1);
    COMPUTE((NT - 2) & 1, NT - 2);
    WAITVM(0);
    WAITLGKM;
    BAR;
    COMPUTE((NT - 1) & 1, NT - 1);

    // ---------------- rowsum reduce across wn quarters
    if (lrow == 0) {
#pragma unroll
        for (int mf = 0; mf < 2; ++mf)
#pragma unroll
            for (int j = 0; j < 4; ++j)
                rsp[wn][wr * 32 + mf * 16 + lk4 * 4 + j] = sums[mf][j];
    }
    __syncthreads();
    if (t < BM)
        rsG[(size_t)ks * N_NODES + m0 + t] = rsp[0][t] + rsp[1][t] + rsp[2][t] + rsp[3][t];

    // ---------------- store f32 partial tile
    float* pp = part + ((size_t)ks * N_NODES + m0) * DOUT;
#pragma unroll
    for (int mf = 0; mf < 2; ++mf)
#pragma unroll
        for (int nf = 0; nf < 4; ++nf) {
            int col = wn * 64 + nf * 16 + lrow;
#pragma unroll
            for (int j = 0; j < 4; ++j) {
                int row = wr * 32 + mf * 16 + lk4 * 4 + j;
                pp[(size_t)row * DOUT + col] = acc[mf][nf][j];
            }
        }
#undef ALOAD
#undef CVTWRITE
#undef BDMA
#undef COMPUTE
}

// ---------------- K2b: pooled = (sum_ks part) / (sum_ks rs + eps), bf16
__global__ __launch_bounds__(256) void k2b_combine(const float* __restrict__ part,
                                                   const float* __restrict__ rsG,
                                                   bf16* __restrict__ pooled) {
    int fl  = blockIdx.x * 256 + threadIdx.x;   // one f32x4 (4 cols) per thread
    int row = fl >> 6;
    int c4  = (fl & 63) * 4;
    f32x4 s = {0.f, 0.f, 0.f, 0.f};
#pragma unroll
    for (int ks = 0; ks < KSPLIT; ++ks) {
        f32x4 v = *reinterpret_cast<const f32x4*>(part + ((size_t)ks * N_NODES + row) * DOUT + c4);
#pragma unroll
        for (int j = 0; j < 4; ++j) s[j] += v[j];
    }
    float rs = EPSF;
#pragma unroll
    for (int ks = 0; ks < KSPLIT; ++ks) rs += rsG[(size_t)ks * N_NODES + row];
    float inv = 1.f / rs;
    bf16x4 o;
#pragma unroll
    for (int j = 0; j < 4; ++j) o[j] = (bf16)(s[j] * inv);
    *reinterpret_cast<bf16x4*>(pooled + (size_t)row * DOUT + c4) = o;
}

// ---------------- K3: out = relu([X || pooled] @ W_fc + b_fc) + eps, + per-block sumsq partial
__global__ __launch_bounds__(128) void k3_out(const float* __restrict__ X,
                                              const bf16* __restrict__ pooled,
                                              const bf16* __restrict__ WfcT,
                                              const float* __restrict__ bfc,
                                              float* __restrict__ out,
                                              float* __restrict__ partials) {
    const int lane = threadIdx.x & 63;
    const int wid  = threadIdx.x >> 6;
    const int m0   = blockIdx.x * 16;
    const int lrow = lane & 15;
    const int lk8  = (lane >> 4) * 8;

    f32x4 acc[8];
#pragma unroll
    for (int i = 0; i < 8; ++i) acc[i] = {0.f, 0.f, 0.f, 0.f};

#pragma unroll
    for (int ks = 0; ks < 256; ks += 32) {
        const float* xp = X + (size_t)(m0 + lrow) * DIN + ks + lk8;
        f32x4 x0 = *reinterpret_cast<const f32x4*>(xp);
        f32x4 x1 = *reinterpret_cast<const f32x4*>(xp + 4);
        bf16x8 a;
#pragma unroll
        for (int j = 0; j < 4; ++j) { a[j] = (bf16)x0[j]; a[4 + j] = (bf16)x1[j]; }
#pragma unroll
        for (int nb = 0; nb < 8; ++nb) {
            int col = wid * 128 + nb * 16 + lrow;
            bf16x8 b = *reinterpret_cast<const bf16x8*>(WfcT + (size_t)col * KCAT + ks + lk8);
            acc[nb] = mfma16(a, b, acc[nb]);
        }
    }
#pragma unroll
    for (int ks = 256; ks < 512; ks += 32) {
        bf16x8 a = *reinterpret_cast<const bf16x8*>(pooled + (size_t)(m0 + lrow) * DOUT + (ks - 256) + lk8);
#pragma unroll
        for (int nb = 0; nb < 8; ++nb) {
            int col = wid * 128 + nb * 16 + lrow;
            bf16x8 b = *reinterpret_cast<const bf16x8*>(WfcT + (size_t)col * KCAT + ks + lk8);
            acc[nb] = mfma16(a, b, acc[nb]);
        }
    }

    float ss = 0.f;
#pragma unroll
    for (int nb = 0; nb < 8; ++nb) {
        int col = wid * 128 + nb * 16 + lrow;
        float bias = bfc[col];
#pragma unroll
        for (int j = 0; j < 4; ++j) {
            int row = m0 + (lane >> 4) * 4 + j;
            float v = acc[nb][j] + bias;
            v = (v > 0.f ? v : 0.f) + EPSF;
            out[(size_t)row * DOUT + col] = v;
            ss += v * v;
        }
    }
#pragma unroll
    for (int off = 32; off; off >>= 1) ss += __shfl_xor(ss, off);
    __shared__ float sw[2];
    if (lane == 0) sw[wid] = ss;
    __syncthreads();
    if (threadIdx.x == 0) partials[blockIdx.x] = sw[0] + sw[1];
}

// ---------------- K4: deterministic reduce of 512 partials; scale out by 1/(norm+eps)
__global__ __launch_bounds__(256) void k4_norm(float* __restrict__ out,
                                               const float* __restrict__ partials) {
    __shared__ float sw[4];
    float s = partials[threadIdx.x] + partials[threadIdx.x + 256];
#pragma unroll
    for (int off = 32; off; off >>= 1) s += __shfl_xor(s, off);
    if ((threadIdx.x & 63) == 0) sw[threadIdx.x >> 6] = s;
    __syncthreads();
    float total = sw[0] + sw[1] + sw[2] + sw[3];
    float scale = 1.f / (sqrtf(total) + EPSF);
    f32x4* o4 = reinterpret_cast<f32x4*>(out);
    const int nvec = N_NODES * DOUT / 4;
    for (int i = blockIdx.x * blockDim.x + threadIdx.x; i < nvec; i += gridDim.x * blockDim.x) {
        f32x4 v = o4[i];
#pragma unroll
        for (int j = 0; j < 4; ++j) v[j] *= scale;
        o4[i] = v;
    }
}

extern "C" void kernel_launch(void* const* d_in, const int* in_sizes, int n_in,
                              void* d_out, int out_size, void* d_ws, size_t ws_size,
                              hipStream_t stream) {
    const float* A   = (const float*)d_in[0];
    const float* X   = (const float*)d_in[1];
    const float* Ww  = (const float*)d_in[2];
    const float* bw  = (const float*)d_in[3];
    const float* Wfc = (const float*)d_in[4];
    const float* bfc = (const float*)d_in[5];
    float* out = (float*)d_out;

    char* ws = (char*)d_ws;
    bf16*  hT        = (bf16*)(ws);                                  // 4 MiB
    bf16*  pooled    = (bf16*)(ws + (4u << 20));                     // 4 MiB
    bf16*  WwT       = (bf16*)(ws + (8u << 20));                     // 128 KiB
    bf16*  WfcT      = (bf16*)(ws + (8u << 20) + (128u << 10));      // 256 KiB
    float* partials  = (float*)(ws + (8u << 20) + (384u << 10));     // 2 KiB
    float* rsG       = (float*)(ws + (8u << 20) + (512u << 10));     // 128 KiB
    float* part      = (float*)(ws + (16u << 20));                   // 32 MiB

    k0_prep<<<512, 256, 0, stream>>>(Ww, Wfc, WwT, WfcT);
    k1_h<<<512, 128, 0, stream>>>(X, WwT, bw, hT);
    k2_pool<<<512, 512, 0, stream>>>(A, hT, part, rsG);
    k2b_combine<<<N_NODES * DOUT / 1024, 256, 0, stream>>>(part, rsG, pooled);
    k3_out<<<512, 128, 0, stream>>>(X, pooled, WfcT, bfc, out, partials);
    k4_norm<<<256, 256, 0, stream>>>(out, partials);
}